// Round 8
// baseline (5503.606 us; speedup 1.0000x reference)
//
#include <hip/hip_runtime.h>
#include <hip/hip_fp16.h>
#include <math.h>

// Problem constants
#define N_ROWS 32768
#define K_CODES 8192
#define DIM 512

// Output layout (floats): quantized_st[N,D], probs[N,K], loss, perplexity
#define OUT_Q 0
#define OUT_P ((size_t)N_ROWS * DIM)                       // 16777216
#define OUT_LOSS (OUT_P + (size_t)N_ROWS * K_CODES)        // 285212672
#define OUT_PERP (OUT_LOSS + 1)

// Workspace layout (float offsets).
#define WS_WSQ 0                        // 8192 floats
#define WS_CNT (K_CODES)                // 8192 floats (histogram)
#define WS_ERR (2 * K_CODES)            // 32768 floats (per-row sq-err)
#define WS_RED (2 * K_CODES + N_ROWS)   // 64 floats (finalize partials)
#define WS_PANEL (WS_RED + 64)          // 128 uints (panel completion counters)
#define WS_F16 (WS_PANEL + 128)         // f16 base (byte 197376, 16-aligned)

// f16 region layout (in _Float16 elements, relative to f16 base)
#define XH_OFF ((size_t)0)
#define XL_OFF ((size_t)N_ROWS * DIM)
#define WH_OFF ((size_t)2 * N_ROWS * DIM)
#define WL_OFF ((size_t)2 * N_ROWS * DIM + (size_t)K_CODES * DIM)
#define F16_COUNT ((size_t)2 * (N_ROWS + K_CODES) * DIM)   // 41943040 halves
#define WS_NEEDED ((size_t)WS_F16 * 4 + F16_COUNT * 2)     // ~84.1 MB

typedef _Float16 f16x8 __attribute__((ext_vector_type(8)));
typedef float f32x4 __attribute__((ext_vector_type(4)));
typedef float f32x2 __attribute__((ext_vector_type(2)));
typedef unsigned long long u64;

__device__ inline void load_lds16(const void* g, void* l) {
    __builtin_amdgcn_global_load_lds((const __attribute__((address_space(1))) void*)g,
                                     (__attribute__((address_space(3))) void*)l,
                                     16, 0, 0);
}

// NT stores only for full-line coalesced never-re-read streams (P).
__device__ inline void ntstore4(float* p, f32x4 v) {
    __builtin_nontemporal_store(v, (f32x4*)p);
}

// Monotone float->uint key: uint order == float order (handles negatives).
__device__ inline unsigned int fkey(float f) {
    unsigned int b = __float_as_uint(f);
    return b ^ ((unsigned int)((int)b >> 31) | 0x80000000u);
}
__device__ inline float fkey_inv(unsigned int k) {
    unsigned int b = (k & 0x80000000u) ? (k ^ 0x80000000u) : ~k;
    return __uint_as_float(b);
}

// ---------------------------------------------------------------------------
// Kernel 0 (fp32 fallback path only): row squared norms for W.
// ---------------------------------------------------------------------------
__global__ void wsq_kernel(const float* __restrict__ W, float* __restrict__ ws) {
    int row = blockIdx.x;
    int lane = threadIdx.x;  // 0..63
    const float* src = W + (size_t)row * DIM;
    float4 v0 = *(const float4*)(src + lane * 8);
    float4 v1 = *(const float4*)(src + lane * 8 + 4);
    float s = v0.x * v0.x + v0.y * v0.y + v0.z * v0.z + v0.w * v0.w
            + v1.x * v1.x + v1.y * v1.y + v1.z * v1.z + v1.w * v1.w;
#pragma unroll
    for (int off = 32; off > 0; off >>= 1) s += __shfl_down(s, off, 64);
    if (lane == 0) ws[WS_WSQ + row] = s;
}

// ---------------------------------------------------------------------------
// Kernel 0b: split X and W into fp16 hi/lo pairs + fused W row norms.
// ---------------------------------------------------------------------------
__global__ void __launch_bounds__(256) convert_split_kernel(
    const float* __restrict__ X, const float* __restrict__ W,
    _Float16* __restrict__ f16base, float* __restrict__ ws) {
    const size_t NX8 = (size_t)N_ROWS * DIM / 8;  // 2097152
    size_t t = (size_t)blockIdx.x * 256 + threadIdx.x;
    const float* src;
    _Float16 *hd, *ld;
    bool isW = (t >= NX8);
    if (!isW) {
        src = X + t * 8;
        hd = f16base + XH_OFF + t * 8;
        ld = f16base + XL_OFF + t * 8;
    } else {
        size_t u = t - NX8;
        src = W + u * 8;
        hd = f16base + WH_OFF + u * 8;
        ld = f16base + WL_OFF + u * 8;
    }
    float4 v0 = *(const float4*)src;
    float4 v1 = *(const float4*)(src + 4);
    float v[8] = {v0.x, v0.y, v0.z, v0.w, v1.x, v1.y, v1.z, v1.w};
    f16x8 h, l;
    float s = 0.f;
#pragma unroll
    for (int i = 0; i < 8; ++i) {
        _Float16 hv = (_Float16)v[i];
        h[i] = hv;
        l[i] = (_Float16)(v[i] - (float)hv);
        s += v[i] * v[i];
    }
    *(f16x8*)hd = h;
    *(f16x8*)ld = l;
    if (isW) {  // wave-uniform branch (W region is wave-aligned)
#pragma unroll
        for (int off = 32; off > 0; off >>= 1) s += __shfl_down(s, off, 64);
        if ((threadIdx.x & 63) == 0) ws[WS_WSQ + ((t - NX8) >> 6)] = s;
    }
}

// ---------------------------------------------------------------------------
// Kernel 1 (MFMA + fused panel-tail softmax):
//   S[m,n] = wsq[n] - 2*(x_m . w_n) via fp16 3-term split (r1 schedule,
//   r1 swizzle, plain S stores - the 903-917us verified config).
// NEW: panel-completion tail fusion. r1 swizzle puts all 64 bn-blocks of a
// bm-panel consecutively on ONE XCD, so a panel's S (17 MB) is L2/L3-hot
// the moment its last block finishes. Each block: threadfence (release S)
// -> syncthreads -> one atomicAdd on panel counter. The block that sees
// old==63 (exactly one; no spinning, no dispatch-order assumption) runs
// the full softmax/argmin/quantize for the panel's 256 rows while other
// CUs continue gemm on later panels. Standalone probs kernel eliminated;
// its ~850us overlaps gemm + S re-read becomes cache-hits.
// ---------------------------------------------------------------------------
#define LDSB 24576   // halves per buffer (Ah 8192 | Al 8192 | Bh 4096 | Bl 4096)
#define AH_O 0
#define AL_O 8192
#define BH_O 16384
#define BL_O 20480

__global__ void __launch_bounds__(512, 2) gemm_dist_mfma_kernel(
    const _Float16* __restrict__ f16base, const float* __restrict__ X,
    const float* __restrict__ W, float* __restrict__ ws,
    float* __restrict__ out) {
    __shared__ __align__(16) _Float16 lds[3 * LDSB];  // 144 KiB

    const int tid = threadIdx.x;
    const int w = tid >> 6;     // wave 0..7
    const int lane = tid & 63;

    // Round-1 XCD swizzle (903us-verified): same-XCD blocks share one bm
    // panel (A-tile L2-resident) and sweep all bn consecutively.
    int lin = blockIdx.y * 64 + blockIdx.x;
    int swz = (lin & 7) * 1024 + (lin >> 3);
    const int bn = (swz & 63) * 128;   // 64 bn tiles
    const int bm = (swz >> 6) * 256;   // 128 bm tiles (= panel id * 256)

    const int wr = w >> 1;      // m-quadrant 0..3 (64 rows each)
    const int wc = w & 1;       // n-half     0..1 (64 cols each)
    const int q = lane >> 4;    // frag k-chunk 0..3
    const int fm = lane & 15;   // frag row/col within 16
    const int l4 = lane >> 2;   // stage: row within 16-row group
    const int p = lane & 3;     // stage: chunk position

    f32x4 acc[4][4];
#pragma unroll
    for (int i = 0; i < 4; ++i)
#pragma unroll
        for (int j = 0; j < 4; ++j) acc[i][j] = (f32x4){0.f, 0.f, 0.f, 0.f};

    auto stage = [&](int ks, _Float16* buf, int part) {
        const int kk = ks * 32;
        int g = w * 2 + part;
        int arow = g * 16 + l4;
        int ca = p ^ ((arow >> 1) & 3);
        size_t aoff = (size_t)(bm + arow) * DIM + kk + ca * 8;
        load_lds16(f16base + XH_OFF + aoff, buf + AH_O + g * 512);
        load_lds16(f16base + XL_OFF + aoff, buf + AL_O + g * 512);
        int brow = w * 16 + l4;
        int cb = p ^ ((brow >> 1) & 3);
        size_t boff = (size_t)(bn + brow) * DIM + kk + cb * 8;
        if (part == 0)
            load_lds16(f16base + WH_OFF + boff, buf + BH_O + w * 512);
        else
            load_lds16(f16base + WL_OFF + boff, buf + BL_O + w * 512);
    };

    _Float16* c0 = lds;
    _Float16* c1 = lds + LDSB;
    _Float16* c2 = lds + 2 * LDSB;

    // Prologue: stage ks0 -> c0 (6 loads), ks1 -> c1 (6 loads); wait for c0.
    stage(0, c0, 0); stage(0, c0, 1);
    stage(1, c1, 0); stage(1, c1, 1);
    asm volatile("s_waitcnt vmcnt(6)" ::: "memory");
    __builtin_amdgcn_s_barrier();
    __builtin_amdgcn_sched_barrier(0);

#pragma unroll 1
    for (int ks = 0; ks < 16; ++ks) {
        // ---- phase 1: all B frags + A(i=0,1); stage part 0 of ks+2 ----
        f16x8 bhv[4], blv[4];
#pragma unroll
        for (int j = 0; j < 4; ++j) {
            int bb = wc * 64 + j * 16 + fm;
            int off = bb * 32 + ((q ^ ((bb >> 1) & 3)) * 8);
            bhv[j] = *(const f16x8*)&c0[BH_O + off];
            blv[j] = *(const f16x8*)&c0[BL_O + off];
        }
        f16x8 ah[2], al[2];
#pragma unroll
        for (int i = 0; i < 2; ++i) {
            int am = wr * 64 + i * 16 + fm;
            int off = am * 32 + ((q ^ ((am >> 1) & 3)) * 8);
            ah[i] = *(const f16x8*)&c0[AH_O + off];
            al[i] = *(const f16x8*)&c0[AL_O + off];
        }
        if (ks < 14) stage(ks + 2, c2, 0);
        __builtin_amdgcn_s_setprio(1);
#pragma unroll
        for (int i = 0; i < 2; ++i)
#pragma unroll
            for (int j = 0; j < 4; ++j) {
                acc[i][j] = __builtin_amdgcn_mfma_f32_16x16x32_f16(
                    ah[i], bhv[j], acc[i][j], 0, 0, 0);
                acc[i][j] = __builtin_amdgcn_mfma_f32_16x16x32_f16(
                    ah[i], blv[j], acc[i][j], 0, 0, 0);
                acc[i][j] = __builtin_amdgcn_mfma_f32_16x16x32_f16(
                    al[i], bhv[j], acc[i][j], 0, 0, 0);
            }
        __builtin_amdgcn_s_setprio(0);
        __builtin_amdgcn_s_barrier();

        // ---- phase 2: A(i=2,3), reuse B frags; stage part 1 of ks+2 ----
#pragma unroll
        for (int i = 0; i < 2; ++i) {
            int am = wr * 64 + (i + 2) * 16 + fm;
            int off = am * 32 + ((q ^ ((am >> 1) & 3)) * 8);
            ah[i] = *(const f16x8*)&c0[AH_O + off];
            al[i] = *(const f16x8*)&c0[AL_O + off];
        }
        if (ks < 14) stage(ks + 2, c2, 1);
        __builtin_amdgcn_s_setprio(1);
#pragma unroll
        for (int i = 0; i < 2; ++i)
#pragma unroll
            for (int j = 0; j < 4; ++j) {
                acc[i + 2][j] = __builtin_amdgcn_mfma_f32_16x16x32_f16(
                    ah[i], bhv[j], acc[i + 2][j], 0, 0, 0);
                acc[i + 2][j] = __builtin_amdgcn_mfma_f32_16x16x32_f16(
                    ah[i], blv[j], acc[i + 2][j], 0, 0, 0);
                acc[i + 2][j] = __builtin_amdgcn_mfma_f32_16x16x32_f16(
                    al[i], bhv[j], acc[i + 2][j], 0, 0, 0);
            }
        __builtin_amdgcn_s_setprio(0);
        // Retire buffer (ks+1)'s 6 loads; keep (ks+2)'s 6 in flight.
        if (ks < 14) {
            asm volatile("s_waitcnt vmcnt(6)" ::: "memory");
        } else if (ks == 14) {
            asm volatile("s_waitcnt vmcnt(0)" ::: "memory");
        }
        __builtin_amdgcn_s_barrier();
        __builtin_amdgcn_sched_barrier(0);

        _Float16* t0 = c0; c0 = c1; c1 = c2; c2 = t0;
    }

    // Epilogue: S = wsq[n] - 2*dot (plain stores; L2 merges partial lines).
    // C/D layout: col = lane&15, row = (lane>>4)*4 + r (m89-verified)
    const float* wsq = ws + WS_WSQ;
    float* Dout = out + OUT_P;
    const int q4 = q * 4;
#pragma unroll
    for (int i = 0; i < 4; ++i) {
#pragma unroll
        for (int j = 0; j < 4; ++j) {
            int n = bn + wc * 64 + j * 16 + fm;
            float wn = wsq[n];
#pragma unroll
            for (int r = 0; r < 4; ++r) {
                int m = bm + wr * 64 + i * 16 + q4 + r;
                Dout[(size_t)m * K_CODES + n] = wn - 2.f * acc[i][j][r];
            }
        }
    }

    // ---- panel completion protocol ----
    // Release: make this block's S stores visible device-wide, then count.
    __threadfence();
    __syncthreads();   // all threads' stores+fences done before the atomic
    unsigned* panel = (unsigned*)(ws + WS_PANEL);
    unsigned* ovp = (unsigned*)lds + 32;  // LDS overlay (K-loop data dead)
    if (tid == 0) ovp[0] = atomicAdd(panel + (bm >> 8), 1u);
    __syncthreads();
    if (ovp[0] != 63u) return;

    // ---- winner: fused softmax/argmin/quantize for rows [bm, bm+256) ----
    {
        u64* mredv = (u64*)lds;               // bytes 0..63
        float* sredv = (float*)lds + 16;      // byte 64
        float* eredv = (float*)lds + 24;      // byte 96
        float* Dbase = out + OUT_P;

        f32x4 eC[4], eN[4];
        auto LOADROW = [&](f32x4* e, int row) {
            const float* Dr = Dbase + (size_t)row * K_CODES;
#pragma unroll
            for (int t = 0; t < 4; ++t)
                e[t] = *(const f32x4*)(Dr + (tid + t * 512) * 4);
        };
        auto PROC = [&](f32x4* e, int row) {
            // packed (min,argmin) over 16 vals/thread
            u64 best = ~0ull;
#pragma unroll
            for (int t = 0; t < 4; ++t) {
                unsigned c0i = (unsigned)((tid + t * 512) * 4);
#pragma unroll
                for (int c = 0; c < 4; ++c) {
                    u64 k = ((u64)fkey(e[t][c]) << 32) | (c0i + c);
                    best = k < best ? k : best;
                }
            }
#pragma unroll
            for (int d = 1; d < 64; d <<= 1) {
                u64 o = __shfl_xor(best, d, 64);
                best = o < best ? o : best;
            }
            if (lane == 0) mredv[w] = best;
            __syncthreads();                              // sync 1
            u64 bmk = mredv[0];
#pragma unroll
            for (int i2 = 1; i2 < 8; ++i2) bmk = mredv[i2] < bmk ? mredv[i2] : bmk;
            const float smin = fkey_inv((unsigned)(bmk >> 32));
            const int amin = (int)(bmk & 0xFFFFFFFFu);
            // issue X and W gathers early (hide under exp phase)
            float xv = X[(size_t)row * DIM + tid];
            float wqv = W[(size_t)amin * DIM + tid];
            // exp + sum
            float sum = 0.f;
#pragma unroll
            for (int t = 0; t < 4; ++t) {
#pragma unroll
                for (int c = 0; c < 4; ++c) {
                    float v = __expf(smin - e[t][c]);
                    e[t][c] = v;
                    sum += v;
                }
            }
#pragma unroll
            for (int off = 32; off > 0; off >>= 1)
                sum += __shfl_down(sum, off, 64);
            if (lane == 0) sredv[w] = sum;
            __syncthreads();                              // sync 2
            float tot = sredv[0];
#pragma unroll
            for (int i2 = 1; i2 < 8; ++i2) tot += sredv[i2];
            const float inv = 1.0f / tot;
            float* Dw = Dbase + (size_t)row * K_CODES;
#pragma unroll
            for (int t = 0; t < 4; ++t) {
                f32x4 v = e[t];
                v *= inv;
                ntstore4(Dw + (tid + t * 512) * 4, v);
            }
            // quantize + straight-through (bit-exact x+(w-x)) + err
            float dq = wqv - xv;
            out[OUT_Q + (size_t)row * DIM + tid] = xv + dq;
            float err = dq * dq;
#pragma unroll
            for (int off = 32; off > 0; off >>= 1)
                err += __shfl_down(err, off, 64);
            if (lane == 0) eredv[w] = err;
            __syncthreads();                              // sync 3
            if (tid == 0) {
                float e8 = eredv[0];
#pragma unroll
                for (int i2 = 1; i2 < 8; ++i2) e8 += eredv[i2];
                ws[WS_ERR + row] = e8;
                atomicAdd(ws + WS_CNT + amin, 1.0f);  // spread over 8192
            }
        };

        LOADROW(eC, bm);
#pragma unroll 1
        for (int r = 0; r < 256; r += 2) {
            LOADROW(eN, bm + r + 1);      // lookahead while eC processes
            PROC(eC, bm + r);
            if (r + 2 < 256) LOADROW(eC, bm + r + 2);
            PROC(eN, bm + r + 1);
        }
    }
}

// ---------------------------------------------------------------------------
// Fallback fp32 GEMM (only if ws can't hold f16 buffers): writes S.
// ---------------------------------------------------------------------------
#define BM 128
#define BN 128
#define BK 16

__global__ void __launch_bounds__(256) gemm_dist_fp32_kernel(
    const float* __restrict__ X, const float* __restrict__ W,
    const float* __restrict__ ws, float* __restrict__ out) {
    __shared__ float As[BK][BM];
    __shared__ float Bs[BK][BN];

    const int bn = blockIdx.x * BN;
    const int bm = blockIdx.y * BM;
    const int tid = threadIdx.x;
    const int tx = tid & 15;
    const int ty = tid >> 4;
    const int lr = tid >> 1;
    const int lc = (tid & 1) * 8;

    float acc[8][8];
#pragma unroll
    for (int i = 0; i < 8; ++i)
#pragma unroll
        for (int j = 0; j < 8; ++j) acc[i][j] = 0.f;

    const float* aptr = X + (size_t)(bm + lr) * DIM + lc;
    const float* bptr = W + (size_t)(bn + lr) * DIM + lc;

    for (int k0 = 0; k0 < DIM; k0 += BK) {
        float4 a0 = *(const float4*)(aptr + k0);
        float4 a1 = *(const float4*)(aptr + k0 + 4);
        float4 b0 = *(const float4*)(bptr + k0);
        float4 b1 = *(const float4*)(bptr + k0 + 4);
        __syncthreads();
        As[lc + 0][lr] = a0.x; As[lc + 1][lr] = a0.y;
        As[lc + 2][lr] = a0.z; As[lc + 3][lr] = a0.w;
        As[lc + 4][lr] = a1.x; As[lc + 5][lr] = a1.y;
        As[lc + 6][lr] = a1.z; As[lc + 7][lr] = a1.w;
        Bs[lc + 0][lr] = b0.x; Bs[lc + 1][lr] = b0.y;
        Bs[lc + 2][lr] = b0.z; Bs[lc + 3][lr] = b0.w;
        Bs[lc + 4][lr] = b1.x; Bs[lc + 5][lr] = b1.y;
        Bs[lc + 6][lr] = b1.z; Bs[lc + 7][lr] = b1.w;
        __syncthreads();
#pragma unroll
        for (int kk = 0; kk < BK; ++kk) {
            float a[8], b[8];
            *(float4*)&a[0] = *(const float4*)&As[kk][ty * 8];
            *(float4*)&a[4] = *(const float4*)&As[kk][ty * 8 + 4];
            *(float4*)&b[0] = *(const float4*)&Bs[kk][tx * 8];
            *(float4*)&b[4] = *(const float4*)&Bs[kk][tx * 8 + 4];
#pragma unroll
            for (int i = 0; i < 8; ++i)
#pragma unroll
                for (int j = 0; j < 8; ++j)
                    acc[i][j] = fmaf(a[i], b[j], acc[i][j]);
        }
    }

    const float* wsq = ws + WS_WSQ;
    const int m0 = bm + ty * 8;
    const int n0 = bn + tx * 8;
    float wn[8];
    *(float4*)&wn[0] = *(const float4*)(wsq + n0);
    *(float4*)&wn[4] = *(const float4*)(wsq + n0 + 4);
    float* Dout = out + OUT_P;
#pragma unroll
    for (int i = 0; i < 8; ++i) {
        float4 o0, o1;
        o0.x = wn[0] - 2.f * acc[i][0];
        o0.y = wn[1] - 2.f * acc[i][1];
        o0.z = wn[2] - 2.f * acc[i][2];
        o0.w = wn[3] - 2.f * acc[i][3];
        o1.x = wn[4] - 2.f * acc[i][4];
        o1.y = wn[5] - 2.f * acc[i][5];
        o1.z = wn[6] - 2.f * acc[i][6];
        o1.w = wn[7] - 2.f * acc[i][7];
        float* drow = Dout + (size_t)(m0 + i) * K_CODES + n0;
        *(float4*)(drow) = o0;
        *(float4*)(drow + 4) = o1;
    }
}

// ---------------------------------------------------------------------------
// Legacy fused probs kernel (fallback path only): 256 thr, two rows/block.
// ---------------------------------------------------------------------------
__global__ void __launch_bounds__(256) probs_quant_kernel(
    const float* __restrict__ X, const float* __restrict__ W,
    float* __restrict__ out, float* __restrict__ ws) {
    const int tid = threadIdx.x;
    const int wv = tid >> 6;
    const int rA = blockIdx.x;
    const int rB = blockIdx.x + N_ROWS / 2;
    __shared__ u64 mred[4];
    __shared__ float sred[4];
    __shared__ float ered[4];

    const float* DA = out + OUT_P + (size_t)rA * K_CODES;
    const float* DB = out + OUT_P + (size_t)rB * K_CODES;

    f32x2 xA = ((const f32x2*)(X + (size_t)rA * DIM))[tid];
    f32x2 xB = ((const f32x2*)(X + (size_t)rB * DIM))[tid];

    f32x4 eA[8];
#pragma unroll
    for (int t = 0; t < 8; ++t)
        eA[t] = *(const f32x4*)(DA + (tid + t * 256) * 4);

    u64 bestA = ~0ull;
#pragma unroll
    for (int t = 0; t < 8; ++t) {
        unsigned int c0 = (unsigned int)((tid + t * 256) * 4);
#pragma unroll
        for (int c = 0; c < 4; ++c) {
            u64 k = ((u64)fkey(eA[t][c]) << 32) | (c0 + c);
            bestA = k < bestA ? k : bestA;
        }
    }
#pragma unroll
    for (int d = 1; d < 64; d <<= 1) {
        u64 o = __shfl_xor(bestA, d, 64);
        bestA = o < bestA ? o : bestA;
    }
    if ((tid & 63) == 0) mred[wv] = bestA;
    __syncthreads();
    u64 bmA = mred[0];
#pragma unroll
    for (int i = 1; i < 4; ++i) bmA = mred[i] < bmA ? mred[i] : bmA;
    const float sminA = fkey_inv((unsigned int)(bmA >> 32));
    const int aminA = (int)(bmA & 0xFFFFFFFFu);

    f32x4 eB[8];
#pragma unroll
    for (int t = 0; t < 8; ++t)
        eB[t] = *(const f32x4*)(DB + (tid + t * 256) * 4);

    float sumA = 0.f;
#pragma unroll
    for (int t = 0; t < 8; ++t) {
#pragma unroll
        for (int c = 0; c < 4; ++c) {
            float v = __expf(sminA - eA[t][c]);
            eA[t][c] = v;
            sumA += v;
        }
    }
#pragma unroll
    for (int off = 32; off > 0; off >>= 1) sumA += __shfl_down(sumA, off, 64);
    if ((tid & 63) == 0) sred[wv] = sumA;
    __syncthreads();
    const float invA = 1.0f / (sred[0] + sred[1] + sred[2] + sred[3]);

    float* DAw = out + OUT_P + (size_t)rA * K_CODES;
#pragma unroll
    for (int t = 0; t < 8; ++t) {
        f32x4 v = eA[t];
        v *= invA;
        ntstore4(DAw + (tid + t * 256) * 4, v);
    }

    {
        f32x2 wq = ((const f32x2*)(W + (size_t)aminA * DIM))[tid];
        f32x2 d = wq - xA;
        f32x2 o = xA + d;
        __builtin_nontemporal_store(
            o, (f32x2*)(out + OUT_Q + (size_t)rA * DIM) + tid);
        float err = d.x * d.x + d.y * d.y;
#pragma unroll
        for (int off = 32; off > 0; off >>= 1) err += __shfl_down(err, off, 64);
        if ((tid & 63) == 0) ered[wv] = err;
        __syncthreads();
        if (tid == 0) {
            ws[WS_ERR + rA] = ered[0] + ered[1] + ered[2] + ered[3];
            atomicAdd(ws + WS_CNT + aminA, 1.0f);
        }
    }

    u64 bestB = ~0ull;
#pragma unroll
    for (int t = 0; t < 8; ++t) {
        unsigned int c0 = (unsigned int)((tid + t * 256) * 4);
#pragma unroll
        for (int c = 0; c < 4; ++c) {
            u64 k = ((u64)fkey(eB[t][c]) << 32) | (c0 + c);
            bestB = k < bestB ? k : bestB;
        }
    }
#pragma unroll
    for (int d = 1; d < 64; d <<= 1) {
        u64 o = __shfl_xor(bestB, d, 64);
        bestB = o < bestB ? o : bestB;
    }
    if ((tid & 63) == 0) mred[wv] = bestB;
    __syncthreads();
    u64 bmB = mred[0];
#pragma unroll
    for (int i = 1; i < 4; ++i) bmB = mred[i] < bmB ? mred[i] : bmB;
    const float sminB = fkey_inv((unsigned int)(bmB >> 32));
    const int aminB = (int)(bmB & 0xFFFFFFFFu);

    float sumB = 0.f;
#pragma unroll
    for (int t = 0; t < 8; ++t) {
#pragma unroll
        for (int c = 0; c < 4; ++c) {
            float v = __expf(sminB - eB[t][c]);
            eB[t][c] = v;
            sumB += v;
        }
    }
#pragma unroll
    for (int off = 32; off > 0; off >>= 1) sumB += __shfl_down(sumB, off, 64);
    if ((tid & 63) == 0) sred[wv] = sumB;
    __syncthreads();
    const float invB = 1.0f / (sred[0] + sred[1] + sred[2] + sred[3]);

    float* DBw = out + OUT_P + (size_t)rB * K_CODES;
#pragma unroll
    for (int t = 0; t < 8; ++t) {
        f32x4 v = eB[t];
        v *= invB;
        ntstore4(DBw + (tid + t * 256) * 4, v);
    }

    {
        f32x2 wq = ((const f32x2*)(W + (size_t)aminB * DIM))[tid];
        f32x2 d = wq - xB;
        f32x2 o = xB + d;
        __builtin_nontemporal_store(
            o, (f32x2*)(out + OUT_Q + (size_t)rB * DIM) + tid);
        float err = d.x * d.x + d.y * d.y;
#pragma unroll
        for (int off = 32; off > 0; off >>= 1) err += __shfl_down(err, off, 64);
        if ((tid & 63) == 0) ered[wv] = err;
        __syncthreads();
        if (tid == 0) {
            ws[WS_ERR + rB] = ered[0] + ered[1] + ered[2] + ered[3];
            atomicAdd(ws + WS_CNT + aminB, 1.0f);
        }
    }
}

// ---------------------------------------------------------------------------
// Kernel 3a: 32-block partial reduce of per-row errors + entropy terms.
// ---------------------------------------------------------------------------
__global__ void __launch_bounds__(256) finalize_part_kernel(
    float* __restrict__ ws) {
    __shared__ float red[256];
    const int b = blockIdx.x;   // 0..31
    const int tid = threadIdx.x;

    float errsum = 0.f;
    const int ebase = b * 1024;
#pragma unroll
    for (int j = tid; j < 1024; j += 256) errsum += ws[WS_ERR + ebase + j];

    float p = ws[WS_CNT + b * 256 + tid] * (1.0f / (float)N_ROWS);
    float ent = -p * logf(p + 1e-10f);

    red[tid] = errsum;
    __syncthreads();
    for (int st = 128; st > 0; st >>= 1) {
        if (tid < st) red[tid] += red[tid + st];
        __syncthreads();
    }
    if (tid == 0) ws[WS_RED + b] = red[0];
    __syncthreads();
    red[tid] = ent;
    __syncthreads();
    for (int st = 128; st > 0; st >>= 1) {
        if (tid < st) red[tid] += red[tid + st];
        __syncthreads();
    }
    if (tid == 0) ws[WS_RED + 32 + b] = red[0];
}

// ---------------------------------------------------------------------------
// Kernel 3b: final combine (one wave).
// ---------------------------------------------------------------------------
__global__ void __launch_bounds__(64) finalize_fin_kernel(
    float* __restrict__ out, const float* __restrict__ ws) {
    const int tid = threadIdx.x;
    float ev = tid < 32 ? ws[WS_RED + tid] : 0.f;
    float nv = tid < 32 ? ws[WS_RED + 32 + tid] : 0.f;
#pragma unroll
    for (int off = 32; off > 0; off >>= 1) {
        ev += __shfl_down(ev, off, 64);
        nv += __shfl_down(nv, off, 64);
    }
    if (tid == 0) {
        float mse = ev * (1.0f / ((float)N_ROWS * (float)DIM));
        out[OUT_LOSS] = mse + 0.25f * mse;
        out[OUT_PERP] = expf(nv);
    }
}

// ---------------------------------------------------------------------------
extern "C" void kernel_launch(void* const* d_in, const int* in_sizes, int n_in,
                              void* d_out, int out_size, void* d_ws, size_t ws_size,
                              hipStream_t stream) {
    const float* X = (const float*)d_in[0];  // [32768, 512]
    const float* W = (const float*)d_in[1];  // [8192, 512]
    float* out = (float*)d_out;
    float* ws = (float*)d_ws;

    // zero histogram + panel counters (ws poisoned 0xAA); rest overwritten
    hipMemsetAsync(ws + WS_CNT, 0, K_CODES * sizeof(float), stream);
    hipMemsetAsync(ws + WS_PANEL, 0, 128 * sizeof(float), stream);

    if (ws_size >= WS_NEEDED) {
        _Float16* f16base = (_Float16*)(ws + WS_F16);
        const int conv_blocks =
            (int)(((size_t)(N_ROWS + K_CODES) * DIM / 8 + 255) / 256);
        // convert also computes wsq (fused W row-norms)
        convert_split_kernel<<<conv_blocks, 256, 0, stream>>>(X, W, f16base, ws);

        // fused gemm + panel-tail softmax/quantize (no separate probs pass)
        dim3 ggrid(64, 128);  // bn-tiles x bm-tiles
        gemm_dist_mfma_kernel<<<ggrid, 512, 0, stream>>>(f16base, X, W, ws, out);
    } else {
        wsq_kernel<<<K_CODES, 64, 0, stream>>>(W, ws);
        dim3 ggrid(K_CODES / BN, N_ROWS / BM);
        gemm_dist_fp32_kernel<<<ggrid, 256, 0, stream>>>(X, W, ws, out);
        probs_quant_kernel<<<N_ROWS / 2, 256, 0, stream>>>(X, W, out, ws);
    }

    finalize_part_kernel<<<32, 256, 0, stream>>>(ws);
    finalize_fin_kernel<<<1, 64, 0, stream>>>(out, ws);
}

// Round 9
// 2273.472 us; speedup vs baseline: 2.4208x; 2.4208x over previous
//
#include <hip/hip_runtime.h>
#include <hip/hip_fp16.h>
#include <math.h>

// Problem constants
#define N_ROWS 32768
#define K_CODES 8192
#define DIM 512

// Output layout (floats): quantized_st[N,D], probs[N,K], loss, perplexity
#define OUT_Q 0
#define OUT_P ((size_t)N_ROWS * DIM)                       // 16777216
#define OUT_LOSS (OUT_P + (size_t)N_ROWS * K_CODES)        // 285212672
#define OUT_PERP (OUT_LOSS + 1)

// Workspace layout (float offsets).
#define WS_WSQ 0                        // 8192 floats
#define WS_CNT (K_CODES)                // 8192 floats (histogram)
#define WS_ERR (2 * K_CODES)            // 32768 floats (per-row sq-err)
#define WS_RED (2 * K_CODES + N_ROWS)   // 64 floats (finalize partials)
#define WS_F16 (WS_RED + 64)            // f16 base (byte 196864, 16-aligned)

// f16 region layout (in _Float16 elements, relative to f16 base)
#define XH_OFF ((size_t)0)
#define XL_OFF ((size_t)N_ROWS * DIM)
#define WH_OFF ((size_t)2 * N_ROWS * DIM)
#define WL_OFF ((size_t)2 * N_ROWS * DIM + (size_t)K_CODES * DIM)
#define F16_COUNT ((size_t)2 * (N_ROWS + K_CODES) * DIM)   // 41943040 halves
#define WS_NEEDED ((size_t)WS_F16 * 4 + F16_COUNT * 2)     // ~84.1 MB

typedef _Float16 f16x8 __attribute__((ext_vector_type(8)));
typedef float f32x4 __attribute__((ext_vector_type(4)));
typedef float f32x2 __attribute__((ext_vector_type(2)));
typedef unsigned long long u64;

__device__ inline void load_lds16(const void* g, void* l) {
    __builtin_amdgcn_global_load_lds((const __attribute__((address_space(1))) void*)g,
                                     (__attribute__((address_space(3))) void*)l,
                                     16, 0, 0);
}

// NT loads for read-once streams (S in probs: keeps 1 GB of dead lines out
// of L2 while P/Q writes stream through). NT stores only for full-line
// coalesced never-re-read streams (P, Q). NT scalar/partial-line stores
// amplify WRITE_SIZE (r6: 1.05->1.40 GB) - never on the gemm epilogue.
__device__ inline f32x4 ntload4(const float* p) {
    return __builtin_nontemporal_load((const f32x4*)p);
}
__device__ inline void ntstore4(float* p, f32x4 v) {
    __builtin_nontemporal_store(v, (f32x4*)p);
}

// Monotone float->uint key: uint order == float order (handles negatives).
__device__ inline unsigned int fkey(float f) {
    unsigned int b = __float_as_uint(f);
    return b ^ ((unsigned int)((int)b >> 31) | 0x80000000u);
}
__device__ inline float fkey_inv(unsigned int k) {
    unsigned int b = (k & 0x80000000u) ? (k ^ 0x80000000u) : ~k;
    return __uint_as_float(b);
}

// ---------------------------------------------------------------------------
// Kernel 0 (fp32 fallback path only): row squared norms for W.
// ---------------------------------------------------------------------------
__global__ void wsq_kernel(const float* __restrict__ W, float* __restrict__ ws) {
    int row = blockIdx.x;
    int lane = threadIdx.x;  // 0..63
    const float* src = W + (size_t)row * DIM;
    float4 v0 = *(const float4*)(src + lane * 8);
    float4 v1 = *(const float4*)(src + lane * 8 + 4);
    float s = v0.x * v0.x + v0.y * v0.y + v0.z * v0.z + v0.w * v0.w
            + v1.x * v1.x + v1.y * v1.y + v1.z * v1.z + v1.w * v1.w;
#pragma unroll
    for (int off = 32; off > 0; off >>= 1) s += __shfl_down(s, off, 64);
    if (lane == 0) ws[WS_WSQ + row] = s;
}

// ---------------------------------------------------------------------------
// Kernel 0b: split X and W into fp16 hi/lo pairs + fused W row norms.
// Plain stores (matches the 903/913us gemm measurements; f16 can L3-cache).
// ---------------------------------------------------------------------------
__global__ void __launch_bounds__(256) convert_split_kernel(
    const float* __restrict__ X, const float* __restrict__ W,
    _Float16* __restrict__ f16base, float* __restrict__ ws) {
    const size_t NX8 = (size_t)N_ROWS * DIM / 8;  // 2097152
    size_t t = (size_t)blockIdx.x * 256 + threadIdx.x;
    const float* src;
    _Float16 *hd, *ld;
    bool isW = (t >= NX8);
    if (!isW) {
        src = X + t * 8;
        hd = f16base + XH_OFF + t * 8;
        ld = f16base + XL_OFF + t * 8;
    } else {
        size_t u = t - NX8;
        src = W + u * 8;
        hd = f16base + WH_OFF + u * 8;
        ld = f16base + WL_OFF + u * 8;
    }
    float4 v0 = *(const float4*)src;
    float4 v1 = *(const float4*)(src + 4);
    float v[8] = {v0.x, v0.y, v0.z, v0.w, v1.x, v1.y, v1.z, v1.w};
    f16x8 h, l;
    float s = 0.f;
#pragma unroll
    for (int i = 0; i < 8; ++i) {
        _Float16 hv = (_Float16)v[i];
        h[i] = hv;
        l[i] = (_Float16)(v[i] - (float)hv);
        s += v[i] * v[i];
    }
    *(f16x8*)hd = h;
    *(f16x8*)ld = l;
    if (isW) {  // wave-uniform branch (W region is wave-aligned)
#pragma unroll
        for (int off = 32; off > 0; off >>= 1) s += __shfl_down(s, off, 64);
        if ((threadIdx.x & 63) == 0) ws[WS_WSQ + ((t - NX8) >> 6)] = s;
    }
}

// ---------------------------------------------------------------------------
// Kernel 1 (MFMA): S[m,n] = wsq[n] - 2 * (x_m . w_n) via fp16 3-term split.
// EXACT r1/r7 configuration (verified 903/913us twice): 2-phase K-step,
// r1 block swizzle, PLAIN epilogue stores. All deviations measured slower:
// 4-phase 1002, 1-barrier 966, stripe swizzle 966, NT epilogue 975,
// panel-tail fusion 4600 (threadfence flushes L2 on non-coherent XCDs).
// ---------------------------------------------------------------------------
#define LDSB 24576   // halves per buffer (Ah 8192 | Al 8192 | Bh 4096 | Bl 4096)
#define AH_O 0
#define AL_O 8192
#define BH_O 16384
#define BL_O 20480

__global__ void __launch_bounds__(512, 2) gemm_dist_mfma_kernel(
    const _Float16* __restrict__ f16base, const float* __restrict__ ws,
    float* __restrict__ out) {
    __shared__ __align__(16) _Float16 lds[3 * LDSB];  // 144 KiB

    const int tid = threadIdx.x;
    const int w = tid >> 6;     // wave 0..7
    const int lane = tid & 63;

    // Round-1 XCD swizzle (903us-verified): same-XCD blocks share one bm
    // (A-tile L2-resident) and sweep all bn.
    int lin = blockIdx.y * 64 + blockIdx.x;
    int swz = (lin & 7) * 1024 + (lin >> 3);
    const int bn = (swz & 63) * 128;   // 64 bn tiles
    const int bm = (swz >> 6) * 256;   // 128 bm tiles

    const int wr = w >> 1;      // m-quadrant 0..3 (64 rows each)
    const int wc = w & 1;       // n-half     0..1 (64 cols each)
    const int q = lane >> 4;    // frag k-chunk 0..3
    const int fm = lane & 15;   // frag row/col within 16
    const int l4 = lane >> 2;   // stage: row within 16-row group
    const int p = lane & 3;     // stage: chunk position

    f32x4 acc[4][4];
#pragma unroll
    for (int i = 0; i < 4; ++i)
#pragma unroll
        for (int j = 0; j < 4; ++j) acc[i][j] = (f32x4){0.f, 0.f, 0.f, 0.f};

    auto stage = [&](int ks, _Float16* buf, int part) {
        const int kk = ks * 32;
        int g = w * 2 + part;
        int arow = g * 16 + l4;
        int ca = p ^ ((arow >> 1) & 3);
        size_t aoff = (size_t)(bm + arow) * DIM + kk + ca * 8;
        load_lds16(f16base + XH_OFF + aoff, buf + AH_O + g * 512);
        load_lds16(f16base + XL_OFF + aoff, buf + AL_O + g * 512);
        int brow = w * 16 + l4;
        int cb = p ^ ((brow >> 1) & 3);
        size_t boff = (size_t)(bn + brow) * DIM + kk + cb * 8;
        if (part == 0)
            load_lds16(f16base + WH_OFF + boff, buf + BH_O + w * 512);
        else
            load_lds16(f16base + WL_OFF + boff, buf + BL_O + w * 512);
    };

    _Float16* c0 = lds;
    _Float16* c1 = lds + LDSB;
    _Float16* c2 = lds + 2 * LDSB;

    // Prologue: stage ks0 -> c0 (6 loads), ks1 -> c1 (6 loads); wait for c0.
    stage(0, c0, 0); stage(0, c0, 1);
    stage(1, c1, 0); stage(1, c1, 1);
    asm volatile("s_waitcnt vmcnt(6)" ::: "memory");
    __builtin_amdgcn_s_barrier();
    __builtin_amdgcn_sched_barrier(0);

#pragma unroll 1
    for (int ks = 0; ks < 16; ++ks) {
        // ---- phase 1: all B frags + A(i=0,1); stage part 0 of ks+2 ----
        f16x8 bhv[4], blv[4];
#pragma unroll
        for (int j = 0; j < 4; ++j) {
            int bb = wc * 64 + j * 16 + fm;
            int off = bb * 32 + ((q ^ ((bb >> 1) & 3)) * 8);
            bhv[j] = *(const f16x8*)&c0[BH_O + off];
            blv[j] = *(const f16x8*)&c0[BL_O + off];
        }
        f16x8 ah[2], al[2];
#pragma unroll
        for (int i = 0; i < 2; ++i) {
            int am = wr * 64 + i * 16 + fm;
            int off = am * 32 + ((q ^ ((am >> 1) & 3)) * 8);
            ah[i] = *(const f16x8*)&c0[AH_O + off];
            al[i] = *(const f16x8*)&c0[AL_O + off];
        }
        if (ks < 14) stage(ks + 2, c2, 0);
        __builtin_amdgcn_s_setprio(1);
#pragma unroll
        for (int i = 0; i < 2; ++i)
#pragma unroll
            for (int j = 0; j < 4; ++j) {
                acc[i][j] = __builtin_amdgcn_mfma_f32_16x16x32_f16(
                    ah[i], bhv[j], acc[i][j], 0, 0, 0);
                acc[i][j] = __builtin_amdgcn_mfma_f32_16x16x32_f16(
                    ah[i], blv[j], acc[i][j], 0, 0, 0);
                acc[i][j] = __builtin_amdgcn_mfma_f32_16x16x32_f16(
                    al[i], bhv[j], acc[i][j], 0, 0, 0);
            }
        __builtin_amdgcn_s_setprio(0);
        __builtin_amdgcn_s_barrier();

        // ---- phase 2: A(i=2,3), reuse B frags; stage part 1 of ks+2 ----
#pragma unroll
        for (int i = 0; i < 2; ++i) {
            int am = wr * 64 + (i + 2) * 16 + fm;
            int off = am * 32 + ((q ^ ((am >> 1) & 3)) * 8);
            ah[i] = *(const f16x8*)&c0[AH_O + off];
            al[i] = *(const f16x8*)&c0[AL_O + off];
        }
        if (ks < 14) stage(ks + 2, c2, 1);
        __builtin_amdgcn_s_setprio(1);
#pragma unroll
        for (int i = 0; i < 2; ++i)
#pragma unroll
            for (int j = 0; j < 4; ++j) {
                acc[i + 2][j] = __builtin_amdgcn_mfma_f32_16x16x32_f16(
                    ah[i], bhv[j], acc[i + 2][j], 0, 0, 0);
                acc[i + 2][j] = __builtin_amdgcn_mfma_f32_16x16x32_f16(
                    ah[i], blv[j], acc[i + 2][j], 0, 0, 0);
                acc[i + 2][j] = __builtin_amdgcn_mfma_f32_16x16x32_f16(
                    al[i], bhv[j], acc[i + 2][j], 0, 0, 0);
            }
        __builtin_amdgcn_s_setprio(0);
        // Retire buffer (ks+1)'s 6 loads; keep (ks+2)'s 6 in flight.
        if (ks < 14) {
            asm volatile("s_waitcnt vmcnt(6)" ::: "memory");
        } else if (ks == 14) {
            asm volatile("s_waitcnt vmcnt(0)" ::: "memory");
        }
        __builtin_amdgcn_s_barrier();
        __builtin_amdgcn_sched_barrier(0);

        _Float16* t0 = c0; c0 = c1; c1 = c2; c2 = t0;
    }

    // Epilogue: S = wsq[n] - 2*dot (plain stores; L2 merges partial lines).
    // C/D layout: col = lane&15, row = (lane>>4)*4 + r (m89-verified)
    const float* wsq = ws + WS_WSQ;
    float* Dout = out + OUT_P;
    const int q4 = q * 4;
#pragma unroll
    for (int i = 0; i < 4; ++i) {
#pragma unroll
        for (int j = 0; j < 4; ++j) {
            int n = bn + wc * 64 + j * 16 + fm;
            float wn = wsq[n];
#pragma unroll
            for (int r = 0; r < 4; ++r) {
                int m = bm + wr * 64 + i * 16 + q4 + r;
                Dout[(size_t)m * K_CODES + n] = wn - 2.f * acc[i][j][r];
            }
        }
    }
}

// ---------------------------------------------------------------------------
// Fallback fp32 GEMM (only if ws can't hold f16 buffers): writes S.
// ---------------------------------------------------------------------------
#define BM 128
#define BN 128
#define BK 16

__global__ void __launch_bounds__(256) gemm_dist_fp32_kernel(
    const float* __restrict__ X, const float* __restrict__ W,
    const float* __restrict__ ws, float* __restrict__ out) {
    __shared__ float As[BK][BM];
    __shared__ float Bs[BK][BN];

    const int bn = blockIdx.x * BN;
    const int bm = blockIdx.y * BM;
    const int tid = threadIdx.x;
    const int tx = tid & 15;
    const int ty = tid >> 4;
    const int lr = tid >> 1;
    const int lc = (tid & 1) * 8;

    float acc[8][8];
#pragma unroll
    for (int i = 0; i < 8; ++i)
#pragma unroll
        for (int j = 0; j < 8; ++j) acc[i][j] = 0.f;

    const float* aptr = X + (size_t)(bm + lr) * DIM + lc;
    const float* bptr = W + (size_t)(bn + lr) * DIM + lc;

    for (int k0 = 0; k0 < DIM; k0 += BK) {
        float4 a0 = *(const float4*)(aptr + k0);
        float4 a1 = *(const float4*)(aptr + k0 + 4);
        float4 b0 = *(const float4*)(bptr + k0);
        float4 b1 = *(const float4*)(bptr + k0 + 4);
        __syncthreads();
        As[lc + 0][lr] = a0.x; As[lc + 1][lr] = a0.y;
        As[lc + 2][lr] = a0.z; As[lc + 3][lr] = a0.w;
        As[lc + 4][lr] = a1.x; As[lc + 5][lr] = a1.y;
        As[lc + 6][lr] = a1.z; As[lc + 7][lr] = a1.w;
        Bs[lc + 0][lr] = b0.x; Bs[lc + 1][lr] = b0.y;
        Bs[lc + 2][lr] = b0.z; Bs[lc + 3][lr] = b0.w;
        Bs[lc + 4][lr] = b1.x; Bs[lc + 5][lr] = b1.y;
        Bs[lc + 6][lr] = b1.z; Bs[lc + 7][lr] = b1.w;
        __syncthreads();
#pragma unroll
        for (int kk = 0; kk < BK; ++kk) {
            float a[8], b[8];
            *(float4*)&a[0] = *(const float4*)&As[kk][ty * 8];
            *(float4*)&a[4] = *(const float4*)&As[kk][ty * 8 + 4];
            *(float4*)&b[0] = *(const float4*)&Bs[kk][tx * 8];
            *(float4*)&b[4] = *(const float4*)&Bs[kk][tx * 8 + 4];
#pragma unroll
            for (int i = 0; i < 8; ++i)
#pragma unroll
                for (int j = 0; j < 8; ++j)
                    acc[i][j] = fmaf(a[i], b[j], acc[i][j]);
        }
    }

    const float* wsq = ws + WS_WSQ;
    const int m0 = bm + ty * 8;
    const int n0 = bn + tx * 8;
    float wn[8];
    *(float4*)&wn[0] = *(const float4*)(wsq + n0);
    *(float4*)&wn[4] = *(const float4*)(wsq + n0 + 4);
    float* Dout = out + OUT_P;
#pragma unroll
    for (int i = 0; i < 8; ++i) {
        float4 o0, o1;
        o0.x = wn[0] - 2.f * acc[i][0];
        o0.y = wn[1] - 2.f * acc[i][1];
        o0.z = wn[2] - 2.f * acc[i][2];
        o0.w = wn[3] - 2.f * acc[i][3];
        o1.x = wn[4] - 2.f * acc[i][4];
        o1.y = wn[5] - 2.f * acc[i][5];
        o1.z = wn[6] - 2.f * acc[i][6];
        o1.w = wn[7] - 2.f * acc[i][7];
        float* drow = Dout + (size_t)(m0 + i) * K_CODES + n0;
        *(float4*)(drow) = o0;
        *(float4*)(drow + 4) = o1;
    }
}

// ---------------------------------------------------------------------------
// Kernel 2 (fused): 256 threads, TWO rows per block (rA = b, rB = b+16384).
// BOTH rows' S loads issued up-front (16 outstanding 16B NT loads/thread -
// max bytes in flight before any reduction dependency). S loads NT (read
// once; keep 1 GB of dead lines out of L2). P/Q stores NT (full-line,
// never re-read). r6-measured best streaming config + deeper load issue.
// ---------------------------------------------------------------------------
__global__ void __launch_bounds__(256) probs_quant_kernel(
    const float* __restrict__ X, const float* __restrict__ W,
    float* __restrict__ out, float* __restrict__ ws) {
    const int tid = threadIdx.x;
    const int wv = tid >> 6;
    const int rA = blockIdx.x;
    const int rB = blockIdx.x + N_ROWS / 2;
    __shared__ u64 mred[4];
    __shared__ float sred[4];
    __shared__ float ered[4];

    const float* DA = out + OUT_P + (size_t)rA * K_CODES;
    const float* DB = out + OUT_P + (size_t)rB * K_CODES;

    // X rows (independent): issue early. One float2/thread = full 512-f row.
    f32x2 xA = ((const f32x2*)(X + (size_t)rA * DIM))[tid];
    f32x2 xB = ((const f32x2*)(X + (size_t)rB * DIM))[tid];

    // ---- both rows' S loads issued up-front (NT) ----
    f32x4 eA[8];
#pragma unroll
    for (int t = 0; t < 8; ++t) eA[t] = ntload4(DA + (tid + t * 256) * 4);
    f32x4 eB[8];
#pragma unroll
    for (int t = 0; t < 8; ++t) eB[t] = ntload4(DB + (tid + t * 256) * 4);

    // ---- row A: packed (min,argmin) ----
    u64 bestA = ~0ull;
#pragma unroll
    for (int t = 0; t < 8; ++t) {
        unsigned int c0 = (unsigned int)((tid + t * 256) * 4);
#pragma unroll
        for (int c = 0; c < 4; ++c) {
            u64 k = ((u64)fkey(eA[t][c]) << 32) | (c0 + c);
            bestA = k < bestA ? k : bestA;
        }
    }
#pragma unroll
    for (int d = 1; d < 64; d <<= 1) {
        u64 o = __shfl_xor(bestA, d, 64);
        bestA = o < bestA ? o : bestA;
    }
    if ((tid & 63) == 0) mred[wv] = bestA;
    __syncthreads();                                   // sync A1
    u64 bmA = mred[0];
#pragma unroll
    for (int i = 1; i < 4; ++i) bmA = mred[i] < bmA ? mred[i] : bmA;
    const float sminA = fkey_inv((unsigned int)(bmA >> 32));
    const int aminA = (int)(bmA & 0xFFFFFFFFu);

    // ---- row A: exp + sum ----
    float sumA = 0.f;
#pragma unroll
    for (int t = 0; t < 8; ++t) {
#pragma unroll
        for (int c = 0; c < 4; ++c) {
            float v = __expf(sminA - eA[t][c]);
            eA[t][c] = v;
            sumA += v;
        }
    }
#pragma unroll
    for (int off = 32; off > 0; off >>= 1) sumA += __shfl_down(sumA, off, 64);
    if ((tid & 63) == 0) sred[wv] = sumA;
    __syncthreads();                                   // sync A2
    const float invA = 1.0f / (sred[0] + sred[1] + sred[2] + sred[3]);

    // ---- row A: normalized NT store ----
    float* DAw = out + OUT_P + (size_t)rA * K_CODES;
#pragma unroll
    for (int t = 0; t < 8; ++t) {
        f32x4 v = eA[t];
        v *= invA;
        ntstore4(DAw + (tid + t * 256) * 4, v);
    }

    // ---- row A: quantize + straight-through + err ----
    {
        f32x2 wq = ((const f32x2*)(W + (size_t)aminA * DIM))[tid];
        f32x2 d = wq - xA;
        f32x2 o = xA + d;  // bit-exact straight-through form
        __builtin_nontemporal_store(
            o, (f32x2*)(out + OUT_Q + (size_t)rA * DIM) + tid);
        float err = d.x * d.x + d.y * d.y;
#pragma unroll
        for (int off = 32; off > 0; off >>= 1) err += __shfl_down(err, off, 64);
        if ((tid & 63) == 0) ered[wv] = err;
        __syncthreads();                               // sync A3
        if (tid == 0) {
            ws[WS_ERR + rA] = ered[0] + ered[1] + ered[2] + ered[3];
            atomicAdd(ws + WS_CNT + aminA, 1.0f);
        }
    }

    // ---- row B: packed (min,argmin) ----
    u64 bestB = ~0ull;
#pragma unroll
    for (int t = 0; t < 8; ++t) {
        unsigned int c0 = (unsigned int)((tid + t * 256) * 4);
#pragma unroll
        for (int c = 0; c < 4; ++c) {
            u64 k = ((u64)fkey(eB[t][c]) << 32) | (c0 + c);
            bestB = k < bestB ? k : bestB;
        }
    }
#pragma unroll
    for (int d = 1; d < 64; d <<= 1) {
        u64 o = __shfl_xor(bestB, d, 64);
        bestB = o < bestB ? o : bestB;
    }
    if ((tid & 63) == 0) mred[wv] = bestB;  // safe: mred-A reads ended before A2
    __syncthreads();                                   // sync B1
    u64 bmB = mred[0];
#pragma unroll
    for (int i = 1; i < 4; ++i) bmB = mred[i] < bmB ? mred[i] : bmB;
    const float sminB = fkey_inv((unsigned int)(bmB >> 32));
    const int aminB = (int)(bmB & 0xFFFFFFFFu);

    // ---- row B: exp + sum ----
    float sumB = 0.f;
#pragma unroll
    for (int t = 0; t < 8; ++t) {
#pragma unroll
        for (int c = 0; c < 4; ++c) {
            float v = __expf(sminB - eB[t][c]);
            eB[t][c] = v;
            sumB += v;
        }
    }
#pragma unroll
    for (int off = 32; off > 0; off >>= 1) sumB += __shfl_down(sumB, off, 64);
    if ((tid & 63) == 0) sred[wv] = sumB;   // safe: sred-A reads ended before A3
    __syncthreads();                                   // sync B2
    const float invB = 1.0f / (sred[0] + sred[1] + sred[2] + sred[3]);

    // ---- row B: normalized NT store ----
    float* DBw = out + OUT_P + (size_t)rB * K_CODES;
#pragma unroll
    for (int t = 0; t < 8; ++t) {
        f32x4 v = eB[t];
        v *= invB;
        ntstore4(DBw + (tid + t * 256) * 4, v);
    }

    // ---- row B: quantize + straight-through + err ----
    {
        f32x2 wq = ((const f32x2*)(W + (size_t)aminB * DIM))[tid];
        f32x2 d = wq - xB;
        f32x2 o = xB + d;
        __builtin_nontemporal_store(
            o, (f32x2*)(out + OUT_Q + (size_t)rB * DIM) + tid);
        float err = d.x * d.x + d.y * d.y;
#pragma unroll
        for (int off = 32; off > 0; off >>= 1) err += __shfl_down(err, off, 64);
        if ((tid & 63) == 0) ered[wv] = err;  // safe: ered-A read ended before B1
        __syncthreads();                               // sync B3
        if (tid == 0) {
            ws[WS_ERR + rB] = ered[0] + ered[1] + ered[2] + ered[3];
            atomicAdd(ws + WS_CNT + aminB, 1.0f);
        }
    }
}

// ---------------------------------------------------------------------------
// Kernel 3a: 32-block partial reduce of per-row errors + entropy terms.
// ---------------------------------------------------------------------------
__global__ void __launch_bounds__(256) finalize_part_kernel(
    float* __restrict__ ws) {
    __shared__ float red[256];
    const int b = blockIdx.x;   // 0..31
    const int tid = threadIdx.x;

    float errsum = 0.f;
    const int ebase = b * 1024;
#pragma unroll
    for (int j = tid; j < 1024; j += 256) errsum += ws[WS_ERR + ebase + j];

    float p = ws[WS_CNT + b * 256 + tid] * (1.0f / (float)N_ROWS);
    float ent = -p * logf(p + 1e-10f);

    red[tid] = errsum;
    __syncthreads();
    for (int st = 128; st > 0; st >>= 1) {
        if (tid < st) red[tid] += red[tid + st];
        __syncthreads();
    }
    if (tid == 0) ws[WS_RED + b] = red[0];
    __syncthreads();
    red[tid] = ent;
    __syncthreads();
    for (int st = 128; st > 0; st >>= 1) {
        if (tid < st) red[tid] += red[tid + st];
        __syncthreads();
    }
    if (tid == 0) ws[WS_RED + 32 + b] = red[0];
}

// ---------------------------------------------------------------------------
// Kernel 3b: final combine (one wave).
// ---------------------------------------------------------------------------
__global__ void __launch_bounds__(64) finalize_fin_kernel(
    float* __restrict__ out, const float* __restrict__ ws) {
    const int tid = threadIdx.x;
    float ev = tid < 32 ? ws[WS_RED + tid] : 0.f;
    float nv = tid < 32 ? ws[WS_RED + 32 + tid] : 0.f;
#pragma unroll
    for (int off = 32; off > 0; off >>= 1) {
        ev += __shfl_down(ev, off, 64);
        nv += __shfl_down(nv, off, 64);
    }
    if (tid == 0) {
        float mse = ev * (1.0f / ((float)N_ROWS * (float)DIM));
        out[OUT_LOSS] = mse + 0.25f * mse;
        out[OUT_PERP] = expf(nv);
    }
}

// ---------------------------------------------------------------------------
extern "C" void kernel_launch(void* const* d_in, const int* in_sizes, int n_in,
                              void* d_out, int out_size, void* d_ws, size_t ws_size,
                              hipStream_t stream) {
    const float* X = (const float*)d_in[0];  // [32768, 512]
    const float* W = (const float*)d_in[1];  // [8192, 512]
    float* out = (float*)d_out;
    float* ws = (float*)d_ws;

    // zero the histogram (ws is poisoned 0xAA); WS_ERR/WS_RED fully overwritten
    hipMemsetAsync(ws + WS_CNT, 0, K_CODES * sizeof(float), stream);

    if (ws_size >= WS_NEEDED) {
        _Float16* f16base = (_Float16*)(ws + WS_F16);
        const int conv_blocks =
            (int)(((size_t)(N_ROWS + K_CODES) * DIM / 8 + 255) / 256);
        // convert also computes wsq (fused W row-norms)
        convert_split_kernel<<<conv_blocks, 256, 0, stream>>>(X, W, f16base, ws);

        dim3 ggrid(64, 128);  // bn-tiles x bm-tiles
        gemm_dist_mfma_kernel<<<ggrid, 512, 0, stream>>>(f16base, ws, out);
    } else {
        wsq_kernel<<<K_CODES, 64, 0, stream>>>(W, ws);
        dim3 ggrid(K_CODES / BN, N_ROWS / BM);
        gemm_dist_fp32_kernel<<<ggrid, 256, 0, stream>>>(X, W, ws, out);
    }

    probs_quant_kernel<<<N_ROWS / 2, 256, 0, stream>>>(X, W, out, ws);
    finalize_part_kernel<<<32, 256, 0, stream>>>(ws);
    finalize_fin_kernel<<<1, 64, 0, stream>>>(out, ws);
}